// Round 14
// baseline (191.728 us; speedup 1.0000x reference)
//
#include <hip/hip_runtime.h>

#define NVERT 6890
#define NFACE 13776
#define SS 256
#define NPIX (SS*SS)
#define TILE 8
#define NSB 256               // superblocks: 2x2 tiles of 8x8 px (16x16 px)
#define SPLIT 16              // face-stream segments per superblock
#define SEGLEN 861            // NFACE / SPLIT (exact: 861*16 = 13776)
#define SENTINEL 0xFFFFFFFFFFFFFFFFULL   // memset-able; high word = NaN bits
#define ZBASE 0x3D000000u     // bucket base (~0.031 as float bits)
#define EYEZ 2.7320508075688776f

// ws layout (byte offsets) — total ~1.63 MB (< 2.09 MB proven safe in round 1)
#define OFF_KEYS 0u           // keys: NPIX*8 = 524,288
#define OFF_FD   524288u      // fd: NFACE*16*4 = 881,664 -> 1,405,952
#define OFF_HIST 1405952u     // hist: 256*4
#define OFF_CURS 1406976u     // cursor: 256*4 (memset 0 with hist)
#define OFF_TD2  1408000u     // td2: NFACE*16 = 220,416 -> ends 1,628,416

static __device__ __forceinline__ unsigned int zbucket(unsigned int zmb) {
  return (zmb > ZBASE) ? min(255u, (zmb - ZBASE) >> 19) : 0u;
}

// ---- exact-rounding helpers (no FMA contraction on the decision path) ----
static __device__ __forceinline__ float edgef(float ax, float ay, float bx, float by,
                                              float px, float py) {
  return __fsub_rn(__fmul_rn(__fsub_rn(ax, px), __fsub_rn(by, py)),
                   __fmul_rn(__fsub_rn(ay, py), __fsub_rn(bx, px)));
}

// texture sampling: one thread per (face, sample t in 0..8); inline vert transform
__global__ __launch_bounds__(256) void tex_k(const float* __restrict__ cam,
                                             const float* __restrict__ verts,
                                             const int* __restrict__ faces,
                                             const float* __restrict__ uv,
                                             float* __restrict__ out_tex) {
  int tid = blockIdx.x * 256 + threadIdx.x;
  if (tid >= NFACE * 9) return;
  int f = tid / 9, t = tid - f * 9;
  int ti = t / 3, tj = t - ti * 3;
  float xt = 0.5f * (float)ti;
  float yt = 0.5f * (float)tj;
  float c0 = cam[0], c1 = cam[1], c2 = cam[2];
  int ia = faces[f*3+0], ib = faces[f*3+1], ic = faces[f*3+2];
  float ax = __fmul_rn(c0, __fadd_rn(verts[ia*3+0], c1));
  float ay = __fmul_rn(c0, __fadd_rn(verts[ia*3+1], c2));
  float bx = __fmul_rn(c0, __fadd_rn(verts[ib*3+0], c1));
  float by = __fmul_rn(c0, __fadd_rn(verts[ib*3+1], c2));
  float cx = __fmul_rn(c0, __fadd_rn(verts[ic*3+0], c1));
  float cy = __fmul_rn(c0, __fadd_rn(verts[ic*3+1], c2));
  float sx = (ax - cx) * xt + (bx - cx) * yt + cx;
  float sy = (ay - cy) * xt + (by - cy) * yt + cy;
  sx = fminf(fmaxf(sx, -1.f), 1.f);
  sy = fminf(fmaxf(sy, -1.f), 1.f);
  float gx = (sx + 1.f) * 128.f - 0.5f;
  float gy = (sy + 1.f) * 128.f - 0.5f;
  float x0f = floorf(gx), y0f = floorf(gy);
  float fx = gx - x0f, fy = gy - y0f;
  int x0 = (int)x0f, y0 = (int)y0f;
  float r = 0.f, g = 0.f, b = 0.f;
  #pragma unroll
  for (int dy = 0; dy < 2; ++dy) {
    #pragma unroll
    for (int dx = 0; dx < 2; ++dx) {
      int xi = x0 + dx, yi = y0 + dy;
      if (xi >= 0 && xi < SS && yi >= 0 && yi < SS) {
        float w = (dx ? fx : 1.f - fx) * (dy ? fy : 1.f - fy);
        int base = yi * SS + xi;
        r += w * uv[base];
        g += w * uv[NPIX + base];
        b += w * uv[2 * NPIX + base];
      }
    }
  }
  float* ot = out_tex + f * 81 + ti * 27 + tj * 9;
  #pragma unroll
  for (int kk = 0; kk < 3; ++kk) {
    ot[kk*3+0] = r; ot[kk*3+1] = g; ot[kk*3+2] = b;
  }
}

// per-face setup (inline vert transform): 64B record + z-bucket histogram
// record: [x0,y0,x1,y1 | x2,y2,rz0,rz1 | rz2,det,c0,c1 | c2,idflag,tilepack,zminbits]
__global__ __launch_bounds__(256) void setup_k(const float* __restrict__ cam,
                                               const float* __restrict__ verts,
                                               const int* __restrict__ faces,
                                               float* __restrict__ fd,
                                               unsigned int* __restrict__ hist) {
  int f = blockIdx.x * 256 + threadIdx.x;
  if (f >= NFACE) return;
  float* fp = fd + (size_t)f * 16;
  float c0 = cam[0], c1 = cam[1], c2 = cam[2];
  int ia = faces[f*3+0], ib = faces[f*3+1], ic = faces[f*3+2];
  float x0 =  __fmul_rn(c0, __fadd_rn(verts[ia*3+0], c1));
  float y0 = -__fmul_rn(c0, __fadd_rn(verts[ia*3+1], c2));
  float z0 =  __fadd_rn(verts[ia*3+2], EYEZ);
  float x1 =  __fmul_rn(c0, __fadd_rn(verts[ib*3+0], c1));
  float y1 = -__fmul_rn(c0, __fadd_rn(verts[ib*3+1], c2));
  float z1 =  __fadd_rn(verts[ib*3+2], EYEZ);
  float x2 =  __fmul_rn(c0, __fadd_rn(verts[ic*3+0], c1));
  float y2 = -__fmul_rn(c0, __fadd_rn(verts[ic*3+1], c2));
  float z2 =  __fadd_rn(verts[ic*3+2], EYEZ);
  float det = edgef(x1, y1, x2, y2, x0, y0);
  unsigned int tilepack = 0x000000FFu;                   // tx0=255 > tx1=0 -> never overlaps
  if (det > 1e-10f) {
    float mnx = fminf(x0, fminf(x1, x2)), mxx = fmaxf(x0, fmaxf(x1, x2));
    float mny = fminf(y0, fminf(y1, y2)), mxy = fmaxf(y0, fmaxf(y1, y2));
    int xlo = max((int)floorf((mnx * 256.f + 255.f) * 0.5f) - 2, 0);
    int xhi = min((int)ceilf ((mxx * 256.f + 255.f) * 0.5f) + 2, SS - 1);
    int ylo = max((int)floorf((mny * 256.f + 255.f) * 0.5f) - 2, 0);
    int yhi = min((int)ceilf ((mxy * 256.f + 255.f) * 0.5f) + 2, SS - 1);
    if (xlo <= xhi && ylo <= yhi)
      tilepack = (unsigned int)(xlo >> 3) | ((unsigned int)(ylo >> 3) << 8)
               | ((unsigned int)(xhi >> 3) << 16) | ((unsigned int)(yhi >> 3) << 24);
  }
  float rz0 = (fabsf(z0) > 1e-8f) ? z0 : 1.0f;
  float rz1 = (fabsf(z1) > 1e-8f) ? z1 : 1.0f;
  float rz2 = (fabsf(z2) > 1e-8f) ? z2 : 1.0f;
  float minrz = fminf(fminf(fabsf(rz0), fabsf(rz1)), fabsf(rz2));
  unsigned int flag = (minrz < 0.05f) ? 1u : 0u;
  unsigned int zmb = 0u;                                 // conservative z-min (harmonic bound)
  if (flag == 0u) {
    float mn = fminf(fminf(rz0, rz1), rz2);
    if (mn > 0.f) zmb = __float_as_uint(mn * 0.999f);
  }
  fp[0] = x0;  fp[1] = y0;  fp[2] = x1;  fp[3] = y1;
  fp[4] = x2;  fp[5] = y2;  fp[6] = rz0; fp[7] = rz1;
  fp[8] = rz2; fp[9] = det;
  fp[10] = __fdiv_rn(1.0f, det * rz0);                   // approx coeffs
  fp[11] = __fdiv_rn(1.0f, det * rz1);
  fp[12] = __fdiv_rn(1.0f, det * rz2);
  fp[13] = __uint_as_float((unsigned int)f | (flag << 24));
  fp[14] = __uint_as_float(tilepack);
  fp[15] = __uint_as_float(zmb);
  atomicAdd(&hist[zbucket(zmb)], 1u);
}

// counting-sort scatter with per-block redundant scan (no separate bscan pass).
// curs[] is memset-0; position = local_excl_scan[bucket] + global intra index.
// pos = (slot%16)*SEGLEN + slot/16 => each segment is an ascending-z stream.
__global__ __launch_bounds__(256) void scatter_k(const float* __restrict__ fd,
                                                 const unsigned int* __restrict__ hist,
                                                 unsigned int* __restrict__ curs,
                                                 uint4* __restrict__ td2) {
  __shared__ unsigned int bsh[256];
  int tid = threadIdx.x;
  unsigned int v = hist[tid];
  bsh[tid] = v;
  __syncthreads();
  for (int off = 1; off < 256; off <<= 1) {
    unsigned int t = (tid >= off) ? bsh[tid - off] : 0u;
    __syncthreads();
    bsh[tid] += t;
    __syncthreads();
  }
  // bsh[b] = inclusive scan; exclusive = bsh[b] - hist[b]
  int f = blockIdx.x * 256 + tid;
  if (f >= NFACE) return;
  const float* fp = fd + (size_t)f * 16;
  unsigned int tilepack = __float_as_uint(fp[14]);
  unsigned int zmb      = __float_as_uint(fp[15]);
  unsigned int b = zbucket(zmb);
  unsigned int slot = (bsh[b] - hist[b]) + atomicAdd(&curs[b], 1u);
  unsigned int pos = (slot & 15u) * SEGLEN + (slot >> 4);
  td2[pos] = make_uint4(tilepack, zmb, (unsigned int)f, 0u);
}

// fused bin+rasterize: block = 2x2 quad of 8x8 tiles; each block streams its
// segment of the z-sorted face list; global z feedback + early break.
__global__ __launch_bounds__(256) void tile_k(const float* __restrict__ fd,
                                              const uint4* __restrict__ td2,
                                              unsigned long long* __restrict__ keys) {
  __shared__ unsigned short idx_s[4][256];
  __shared__ unsigned int cnt_s[4];
  __shared__ unsigned int wmax_s[4];
  int sb  = blockIdx.x & (NSB - 1);
  int seg = blockIdx.x >> 8;         // 0..SPLIT-1
  int tid = threadIdx.x;
  int w = tid >> 6, lane = tid & 63;
  int sbx = sb & 15, sby = sb >> 4;
  int tx = sbx * 2 + (w & 1);        // this wave's 8-px tile coords (0..31)
  int ty = sby * 2 + (w >> 1);
  int xx = tx * TILE + (lane & 7);
  int yy = ty * TILE + (lane >> 3);
  float px = (float)(2 * xx + 1 - SS) * (1.0f / 256.0f);   // exact
  float py = (float)(2 * yy + 1 - SS) * (1.0f / 256.0f);
  int p = yy * SS + xx;
  unsigned long long best = SENTINEL;      // purely LOCAL candidates
  unsigned long long lastw = SENTINEL;     // last value merged to keys
  const uint4* tseg = td2 + (size_t)seg * SEGLEN;

  for (int base = 0; base < SEGLEN; base += 256) {
    // global z feedback: any stored high-word is a real candidate's z
    unsigned int gz = (unsigned int)(keys[p] >> 32);
    unsigned int kz = min((unsigned int)(best >> 32), gz);
    unsigned int bh = kz;
    #pragma unroll
    for (int o = 32; o > 0; o >>= 1)
      bh = max(bh, (unsigned int)__shfl_xor((int)bh, o, 64));
    __syncthreads();                       // A: previous consume done
    if (lane == 0) wmax_s[w] = bh;
    if (tid < 4) cnt_s[tid] = 0;
    __syncthreads();                       // B: wmax/cnt visible
    // early exit: ascending stream => remaining zmb >= bucket lower bound
    unsigned int bm = max(max(wmax_s[0], wmax_s[1]), max(wmax_s[2], wmax_s[3]));
    unsigned int z0 = tseg[base].y;
    unsigned int b0 = zbucket(z0);
    unsigned int lb = b0 ? (ZBASE + (b0 << 19)) : 0u;
    if (lb > bm) break;                    // uniform across block
    int fi = base + tid;
    if (fi < SEGLEN) {
      uint4 t2 = tseg[fi];
      unsigned int tp = t2.x, zmb = t2.y;
      int tx0 = (int)(tp & 255u),         ty0 = (int)((tp >> 8) & 255u);
      int tx1 = (int)((tp >> 16) & 255u), ty1 = (int)(tp >> 24);
      #pragma unroll
      for (int q = 0; q < 4; ++q) {
        int qtx = sbx * 2 + (q & 1);
        int qty = sby * 2 + (q >> 1);
        if (qtx >= tx0 && qtx <= tx1 && qty >= ty0 && qty <= ty1
            && zmb <= wmax_s[q]) {
          unsigned int slot = atomicAdd(&cnt_s[q], 1u);   // LDS atomic, <=256
          idx_s[q][slot] = (unsigned short)t2.z;
        }
      }
    }
    __syncthreads();                       // C: appends visible
    int m = (int)cnt_s[w];
    for (int j = 0; j < m; ++j) {
      int f2 = __builtin_amdgcn_readfirstlane((int)idx_s[w][j]);  // scalar addr
      const float4* fr = (const float4*)(fd + (size_t)f2 * 16);
      float4 A  = fr[0];                   // x0,y0,x1,y1
      float4 Bv = fr[1];                   // x2,y2,rz0,rz1
      float4 Cv = fr[2];                   // rz2,det,c0,c1
      float4 Dv = fr[3];                   // c2,idflag,tilepack,zminbits
      unsigned int zmb = __float_as_uint(Dv.w);
      if (zmb > kz) continue;              // per-lane z-kill (strict)
      float e0 = edgef(A.z, A.w, Bv.x, Bv.y, px, py);
      float e1 = edgef(Bv.x, Bv.y, A.x, A.y, px, py);
      float e2 = edgef(A.x, A.y, A.z, A.w, px, py);
      if (e0 >= 0.f && e1 >= 0.f && e2 >= 0.f) {
        float inva = __fmaf_rn(e0, Cv.z, __fmaf_rn(e1, Cv.w, e2 * Dv.x));
        float zc = __uint_as_float(kz);    // conservative threshold
        unsigned int w13 = __float_as_uint(Dv.y);
        bool pass = (kz >= 0x7F800000u)    // no candidate yet (sentinel/NaN bits)
                  | ((w13 >> 24) != 0u) | (inva * zc > 0.998f) | (fabsf(inva) < 1e-4f);
        if (pass) {
          // exact reference chain (bit-identical decision path)
          float rz0 = Bv.z, rz1 = Bv.w, rz2 = Cv.x, det = Cv.y;
          float b0f = __fdiv_rn(e0, det);
          float b1f = __fdiv_rn(e1, det);
          float b2f = __fdiv_rn(e2, det);
          float inv = __fadd_rn(__fadd_rn(__fdiv_rn(b0f, rz0), __fdiv_rn(b1f, rz1)),
                                __fdiv_rn(b2f, rz2));
          if (!(fabsf(inv) > 1e-8f)) inv = 1.0f;
          float zp = __fdiv_rn(1.0f, inv);
          if (zp > 0.1f && zp < 25.0f) {
            unsigned long long key =
                ((unsigned long long)__float_as_uint(zp) << 32)
                | (w13 & 0x00FFFFFFu);
            if (key < best) {
              best = key;
              kz = min(kz, (unsigned int)(best >> 32));
            }
          }
        }
      }
    }
    // eager merge: only if local z can match/beat achieved global z (safe:
    // a strictly-greater z loses regardless of face id)
    if (best != lastw && (unsigned int)(best >> 32) <= gz) {
      atomicMin(&keys[p], best);
      lastw = best;
    }
  }
}

// resolve: one thread per pixel -> images output (exact chain, inline transform)
__global__ __launch_bounds__(256) void resolve_k(const float* __restrict__ cam,
                                                 const float* __restrict__ verts,
                                                 const int* __restrict__ faces,
                                                 const unsigned long long* __restrict__ keys,
                                                 const float* __restrict__ out_tex,
                                                 float* __restrict__ out_img) {
  int p = blockIdx.x * 256 + threadIdx.x;
  if (p >= NPIX) return;
  unsigned long long k = keys[p];
  float c0v = 0.f, c1v = 0.f, c2v = 0.f;
  if (k != SENTINEL) {
    int f = (int)(unsigned int)(k & 0x00FFFFFFULL);
    float bz = __uint_as_float((unsigned int)(k >> 32));
    int xx = p & (SS - 1), yy = p >> 8;
    float px = (float)(2 * xx + 1 - SS) * (1.0f / 256.0f);
    float py = (float)(2 * yy + 1 - SS) * (1.0f / 256.0f);
    float c0 = cam[0], c1 = cam[1], c2 = cam[2];
    int ia = faces[f*3+0], ib = faces[f*3+1], ic = faces[f*3+2];
    float x0 =  __fmul_rn(c0, __fadd_rn(verts[ia*3+0], c1));
    float y0 = -__fmul_rn(c0, __fadd_rn(verts[ia*3+1], c2));
    float z0 =  __fadd_rn(verts[ia*3+2], EYEZ);
    float x1 =  __fmul_rn(c0, __fadd_rn(verts[ib*3+0], c1));
    float y1 = -__fmul_rn(c0, __fadd_rn(verts[ib*3+1], c2));
    float z1 =  __fadd_rn(verts[ib*3+2], EYEZ);
    float x2 =  __fmul_rn(c0, __fadd_rn(verts[ic*3+0], c1));
    float y2 = -__fmul_rn(c0, __fadd_rn(verts[ic*3+1], c2));
    float z2 =  __fadd_rn(verts[ic*3+2], EYEZ);
    float det = edgef(x1, y1, x2, y2, x0, y0);
    float e0 = edgef(x1, y1, x2, y2, px, py);
    float e1 = edgef(x2, y2, x0, y0, px, py);
    float e2 = edgef(x0, y0, x1, y1, px, py);
    float b0 = __fdiv_rn(e0, det);
    float b1 = __fdiv_rn(e1, det);
    float b2 = __fdiv_rn(e2, det);
    float rz0 = (fabsf(z0) > 1e-8f) ? z0 : 1.0f;
    float rz1 = (fabsf(z1) > 1e-8f) ? z1 : 1.0f;
    float rz2 = (fabsf(z2) > 1e-8f) ? z2 : 1.0f;
    float w0 = __fmul_rn(__fdiv_rn(b0, rz0), bz);
    float w1 = __fmul_rn(__fdiv_rn(b1, rz1), bz);
    float w2 = __fmul_rn(__fdiv_rn(b2, rz2), bz);
    float pos0 = fminf(fmaxf(w0, 0.f), 1.f) * 2.f;
    float pos1 = fminf(fmaxf(w1, 0.f), 1.f) * 2.f;
    float pos2 = fminf(fmaxf(w2, 0.f), 1.f) * 2.f;
    float i0f = fminf(fmaxf(floorf(pos0), 0.f), 1.f);
    float i1f = fminf(fmaxf(floorf(pos1), 0.f), 1.f);
    float i2f = fminf(fmaxf(floorf(pos2), 0.f), 1.f);
    float fr0 = fminf(fmaxf(__fsub_rn(pos0, i0f), 0.f), 1.f);
    float fr1 = fminf(fmaxf(__fsub_rn(pos1, i1f), 0.f), 1.f);
    float fr2 = fminf(fmaxf(__fsub_rn(pos2, i2f), 0.f), 1.f);
    int i00 = (int)i0f, i01 = (int)i1f;
    #pragma unroll
    for (int d0 = 0; d0 < 2; ++d0) {
      float wa = d0 ? fr0 : __fsub_rn(1.f, fr0);
      #pragma unroll
      for (int d1 = 0; d1 < 2; ++d1) {
        float wb = d1 ? fr1 : __fsub_rn(1.f, fr1);
        int a = min(i00 + d0, 2);
        int b = min(i01 + d1, 2);
        const float* tp = &out_tex[f * 81 + a * 27 + b * 9];  // k=0 slice
        float wab = __fmul_rn(wa, wb);
        #pragma unroll
        for (int d2 = 0; d2 < 2; ++d2) {
          float wc = d2 ? fr2 : __fsub_rn(1.f, fr2);
          float wgt = __fmul_rn(wab, wc);
          c0v = __fadd_rn(c0v, __fmul_rn(wgt, tp[0]));
          c1v = __fadd_rn(c1v, __fmul_rn(wgt, tp[1]));
          c2v = __fadd_rn(c2v, __fmul_rn(wgt, tp[2]));
        }
      }
    }
  }
  out_img[p]          = c0v;
  out_img[NPIX + p]   = c1v;
  out_img[2*NPIX + p] = c2v;
}

extern "C" void kernel_launch(void* const* d_in, const int* in_sizes, int n_in,
                              void* d_out, int out_size, void* d_ws, size_t ws_size,
                              hipStream_t stream) {
  const float* cam   = (const float*)d_in[0];
  const float* verts = (const float*)d_in[1];
  const float* uv    = (const float*)d_in[2];
  const int*   faces = (const int*)d_in[3];
  float* out_img = (float*)d_out;            // (1,3,256,256)
  float* out_tex = (float*)d_out + 3 * NPIX; // (1,NF,3,3,3,3)

  char* ws = (char*)d_ws;
  unsigned long long* keys = (unsigned long long*)(ws + OFF_KEYS);
  float* fd          = (float*)(ws + OFF_FD);
  unsigned int* hist = (unsigned int*)(ws + OFF_HIST);
  unsigned int* curs = (unsigned int*)(ws + OFF_CURS);
  uint4* td2         = (uint4*)(ws + OFF_TD2);

  hipMemsetAsync(keys, 0xFF, (size_t)NPIX * 8, stream);      // SENTINEL
  hipMemsetAsync(hist, 0, 2048, stream);                     // hist + curs
  setup_k<<<(NFACE + 255) / 256, 256, 0, stream>>>(cam, verts, faces, fd, hist);
  tex_k<<<(NFACE * 9 + 255) / 256, 256, 0, stream>>>(cam, verts, faces, uv, out_tex);
  scatter_k<<<(NFACE + 255) / 256, 256, 0, stream>>>(fd, hist, curs, td2);
  tile_k<<<NSB * SPLIT, 256, 0, stream>>>(fd, td2, keys);
  resolve_k<<<NPIX / 256, 256, 0, stream>>>(cam, verts, faces, keys, out_tex, out_img);
}

// Round 15
// 164.582 us; speedup vs baseline: 1.1649x; 1.1649x over previous
//
#include <hip/hip_runtime.h>

#define NVERT 6890
#define NFACE 13776
#define SS 256
#define NPIX (SS*SS)
#define TILE 8
#define NSB 256               // superblocks: 2x2 tiles of 8x8 px (16x16 px)
#define SPLIT 16              // face-stream segments per superblock
#define SEGLEN 861            // NFACE / SPLIT (exact: 861*16 = 13776)
#define NSETUPBLK 54          // ceil(NFACE/256)
#define SENTINEL 0xFFFFFFFFFFFFFFFFULL
#define ZBASE 0x3D000000u     // bucket base (~0.031 as float bits)
#define EYEZ 2.7320508075688776f

// ws layout (byte offsets) — total ~1.68 MB (< 2.09 MB proven safe in round 1)
#define OFF_KEYS 0u           // keys: NPIX*8 = 524,288
#define OFF_FD   524288u      // fd: NFACE*16*4 = 881,664 -> 1,405,952
#define OFF_PH   1405952u     // phist: 54*256*4 = 55,296 -> 1,461,248
#define OFF_TD2  1461248u     // td2: NFACE*16 = 220,416 -> ends 1,681,664

static __device__ __forceinline__ unsigned int zbucket(unsigned int zmb) {
  return (zmb > ZBASE) ? min(255u, (zmb - ZBASE) >> 19) : 0u;
}

// ---- exact-rounding helpers (no FMA contraction on the decision path) ----
static __device__ __forceinline__ float edgef(float ax, float ay, float bx, float by,
                                              float px, float py) {
  return __fsub_rn(__fmul_rn(__fsub_rn(ax, px), __fsub_rn(by, py)),
                   __fmul_rn(__fsub_rn(ay, py), __fsub_rn(bx, px)));
}

// fused prep: keys init + per-face setup (+LDS partial histogram) + texture pass
__global__ __launch_bounds__(256) void prep_k(const float* __restrict__ cam,
                                              const float* __restrict__ verts,
                                              const int* __restrict__ faces,
                                              const float* __restrict__ uv,
                                              float* __restrict__ fd,
                                              unsigned int* __restrict__ phist,
                                              unsigned long long* __restrict__ keys,
                                              float* __restrict__ out_tex) {
  __shared__ unsigned int lh[256];
  int blk = blockIdx.x;
  int tid = threadIdx.x;
  int i = blk * 256 + tid;
  bool hblk = (blk < NSETUPBLK);
  if (hblk) lh[tid] = 0u;
  if (i < NPIX) keys[i] = SENTINEL;
  float c0 = cam[0], c1 = cam[1], c2 = cam[2];

  // ---- per-face setup ----
  unsigned int mybucket = 0u;
  bool isface = (i < NFACE);
  if (isface) {
    int f = i;
    float* fp = fd + (size_t)f * 16;
    int ia = faces[f*3+0], ib = faces[f*3+1], ic = faces[f*3+2];
    float x0 =  __fmul_rn(c0, __fadd_rn(verts[ia*3+0], c1));
    float y0 = -__fmul_rn(c0, __fadd_rn(verts[ia*3+1], c2));
    float z0 =  __fadd_rn(verts[ia*3+2], EYEZ);
    float x1 =  __fmul_rn(c0, __fadd_rn(verts[ib*3+0], c1));
    float y1 = -__fmul_rn(c0, __fadd_rn(verts[ib*3+1], c2));
    float z1 =  __fadd_rn(verts[ib*3+2], EYEZ);
    float x2 =  __fmul_rn(c0, __fadd_rn(verts[ic*3+0], c1));
    float y2 = -__fmul_rn(c0, __fadd_rn(verts[ic*3+1], c2));
    float z2 =  __fadd_rn(verts[ic*3+2], EYEZ);
    float det = edgef(x1, y1, x2, y2, x0, y0);
    unsigned int tilepack = 0x000000FFu;               // never overlaps
    if (det > 1e-10f) {
      float mnx = fminf(x0, fminf(x1, x2)), mxx = fmaxf(x0, fmaxf(x1, x2));
      float mny = fminf(y0, fminf(y1, y2)), mxy = fmaxf(y0, fmaxf(y1, y2));
      int xlo = max((int)floorf((mnx * 256.f + 255.f) * 0.5f) - 2, 0);
      int xhi = min((int)ceilf ((mxx * 256.f + 255.f) * 0.5f) + 2, SS - 1);
      int ylo = max((int)floorf((mny * 256.f + 255.f) * 0.5f) - 2, 0);
      int yhi = min((int)ceilf ((mxy * 256.f + 255.f) * 0.5f) + 2, SS - 1);
      if (xlo <= xhi && ylo <= yhi)
        tilepack = (unsigned int)(xlo >> 3) | ((unsigned int)(ylo >> 3) << 8)
                 | ((unsigned int)(xhi >> 3) << 16) | ((unsigned int)(yhi >> 3) << 24);
    }
    float rz0 = (fabsf(z0) > 1e-8f) ? z0 : 1.0f;
    float rz1 = (fabsf(z1) > 1e-8f) ? z1 : 1.0f;
    float rz2 = (fabsf(z2) > 1e-8f) ? z2 : 1.0f;
    float minrz = fminf(fminf(fabsf(rz0), fabsf(rz1)), fabsf(rz2));
    unsigned int flag = (minrz < 0.05f) ? 1u : 0u;
    unsigned int zmb = 0u;                             // conservative z-min (harmonic bound)
    if (flag == 0u) {
      float mn = fminf(fminf(rz0, rz1), rz2);
      if (mn > 0.f) zmb = __float_as_uint(mn * 0.999f);
    }
    fp[0] = x0;  fp[1] = y0;  fp[2] = x1;  fp[3] = y1;
    fp[4] = x2;  fp[5] = y2;  fp[6] = rz0; fp[7] = rz1;
    fp[8] = rz2; fp[9] = det;
    fp[10] = __fdiv_rn(1.0f, det * rz0);               // approx coeffs
    fp[11] = __fdiv_rn(1.0f, det * rz1);
    fp[12] = __fdiv_rn(1.0f, det * rz2);
    fp[13] = __uint_as_float((unsigned int)f | (flag << 24));
    fp[14] = __uint_as_float(tilepack);
    fp[15] = __uint_as_float(zmb);
    mybucket = zbucket(zmb);
  }
  if (hblk) {
    __syncthreads();                     // uniform per block
    if (isface) atomicAdd(&lh[mybucket], 1u);
    __syncthreads();
    phist[blk * 256 + tid] = lh[tid];
  }

  // ---- texture pass: thread i -> (face i/9, sample i%9) ----
  if (i < NFACE * 9) {
    int f = i / 9, t = i - f * 9;
    int ti = t / 3, tj = t - ti * 3;
    float xt = 0.5f * (float)ti;
    float yt = 0.5f * (float)tj;
    int ia = faces[f*3+0], ib = faces[f*3+1], ic = faces[f*3+2];
    float ax = __fmul_rn(c0, __fadd_rn(verts[ia*3+0], c1));
    float ay = __fmul_rn(c0, __fadd_rn(verts[ia*3+1], c2));
    float bx = __fmul_rn(c0, __fadd_rn(verts[ib*3+0], c1));
    float by = __fmul_rn(c0, __fadd_rn(verts[ib*3+1], c2));
    float cx = __fmul_rn(c0, __fadd_rn(verts[ic*3+0], c1));
    float cy = __fmul_rn(c0, __fadd_rn(verts[ic*3+1], c2));
    float sx = (ax - cx) * xt + (bx - cx) * yt + cx;
    float sy = (ay - cy) * xt + (by - cy) * yt + cy;
    sx = fminf(fmaxf(sx, -1.f), 1.f);
    sy = fminf(fmaxf(sy, -1.f), 1.f);
    float gx = (sx + 1.f) * 128.f - 0.5f;
    float gy = (sy + 1.f) * 128.f - 0.5f;
    float x0f = floorf(gx), y0f = floorf(gy);
    float fx = gx - x0f, fy = gy - y0f;
    int x0 = (int)x0f, y0 = (int)y0f;
    float r = 0.f, g = 0.f, b = 0.f;
    #pragma unroll
    for (int dy = 0; dy < 2; ++dy) {
      #pragma unroll
      for (int dx = 0; dx < 2; ++dx) {
        int xi = x0 + dx, yi = y0 + dy;
        if (xi >= 0 && xi < SS && yi >= 0 && yi < SS) {
          float w = (dx ? fx : 1.f - fx) * (dy ? fy : 1.f - fy);
          int base = yi * SS + xi;
          r += w * uv[base];
          g += w * uv[NPIX + base];
          b += w * uv[2 * NPIX + base];
        }
      }
    }
    float* ot = out_tex + f * 81 + ti * 27 + tj * 9;
    #pragma unroll
    for (int kk = 0; kk < 3; ++kk) {
      ot[kk*3+0] = r; ot[kk*3+1] = g; ot[kk*3+2] = b;
    }
  }
}

// single-block: reduce partial hists -> scan -> counting-sort scatter.
// pos = (slot%16)*SEGLEN + slot/16 => each segment is an ascending-z stream.
__global__ __launch_bounds__(1024) void scatter_k(const float* __restrict__ fd,
                                                  const unsigned int* __restrict__ phist,
                                                  uint4* __restrict__ td2) {
  __shared__ unsigned int part[1024];
  __shared__ unsigned int sc[256];
  __shared__ unsigned int excl[256];
  __shared__ unsigned int curs[256];
  int tid = threadIdx.x;
  unsigned int b255 = (unsigned int)(tid & 255), strip = (unsigned int)(tid >> 8);
  unsigned int s = 0;
  for (unsigned int bb = strip; bb < NSETUPBLK; bb += 4)
    s += phist[bb * 256 + b255];
  part[tid] = s;
  __syncthreads();
  unsigned int v = 0;
  if (tid < 256) {
    v = part[tid] + part[tid + 256] + part[tid + 512] + part[tid + 768];
    sc[tid] = v;
    curs[tid] = 0u;
  }
  __syncthreads();
  for (int off = 1; off < 256; off <<= 1) {
    unsigned int t_ = 0;
    if (tid < 256 && tid >= off) t_ = sc[tid - off];
    __syncthreads();
    if (tid < 256) sc[tid] += t_;
    __syncthreads();
  }
  if (tid < 256) excl[tid] = sc[tid] - v;
  __syncthreads();
  for (int f = tid; f < NFACE; f += 1024) {
    const float* fp = fd + (size_t)f * 16;
    unsigned int tilepack = __float_as_uint(fp[14]);
    unsigned int zmb      = __float_as_uint(fp[15]);
    unsigned int b = zbucket(zmb);
    unsigned int slot = excl[b] + atomicAdd(&curs[b], 1u);
    unsigned int pos = (slot & 15u) * SEGLEN + (slot >> 4);
    td2[pos] = make_uint4(tilepack, zmb, (unsigned int)f, 0u);
  }
}

// fused bin+rasterize: block = 2x2 quad of 8x8 tiles; each block streams its
// segment of the z-sorted face list; global z feedback + early break.
__global__ __launch_bounds__(256) void tile_k(const float* __restrict__ fd,
                                              const uint4* __restrict__ td2,
                                              unsigned long long* __restrict__ keys) {
  __shared__ unsigned short idx_s[4][256];
  __shared__ unsigned int cnt_s[4];
  __shared__ unsigned int wmax_s[4];
  int sb  = blockIdx.x & (NSB - 1);
  int seg = blockIdx.x >> 8;         // 0..SPLIT-1
  int tid = threadIdx.x;
  int w = tid >> 6, lane = tid & 63;
  int sbx = sb & 15, sby = sb >> 4;
  int tx = sbx * 2 + (w & 1);        // this wave's 8-px tile coords (0..31)
  int ty = sby * 2 + (w >> 1);
  int xx = tx * TILE + (lane & 7);
  int yy = ty * TILE + (lane >> 3);
  float px = (float)(2 * xx + 1 - SS) * (1.0f / 256.0f);   // exact
  float py = (float)(2 * yy + 1 - SS) * (1.0f / 256.0f);
  int p = yy * SS + xx;
  unsigned long long best = SENTINEL;      // purely LOCAL candidates
  unsigned long long lastw = SENTINEL;     // last value merged to keys
  const uint4* tseg = td2 + (size_t)seg * SEGLEN;

  for (int base = 0; base < SEGLEN; base += 256) {
    // global z feedback: any stored high-word is a real candidate's z
    unsigned int gz = (unsigned int)(keys[p] >> 32);
    unsigned int kz = min((unsigned int)(best >> 32), gz);
    unsigned int bh = kz;
    #pragma unroll
    for (int o = 32; o > 0; o >>= 1)
      bh = max(bh, (unsigned int)__shfl_xor((int)bh, o, 64));
    __syncthreads();                       // A: previous consume done
    if (lane == 0) wmax_s[w] = bh;
    if (tid < 4) cnt_s[tid] = 0;
    __syncthreads();                       // B: wmax/cnt visible
    // early exit: ascending stream => remaining zmb >= bucket lower bound
    unsigned int bm = max(max(wmax_s[0], wmax_s[1]), max(wmax_s[2], wmax_s[3]));
    unsigned int z0 = tseg[base].y;
    unsigned int b0 = zbucket(z0);
    unsigned int lb = b0 ? (ZBASE + (b0 << 19)) : 0u;
    if (lb > bm) break;                    // uniform across block
    int fi = base + tid;
    if (fi < SEGLEN) {
      uint4 t2 = tseg[fi];
      unsigned int tp = t2.x, zmb = t2.y;
      int tx0 = (int)(tp & 255u),         ty0 = (int)((tp >> 8) & 255u);
      int tx1 = (int)((tp >> 16) & 255u), ty1 = (int)(tp >> 24);
      #pragma unroll
      for (int q = 0; q < 4; ++q) {
        int qtx = sbx * 2 + (q & 1);
        int qty = sby * 2 + (q >> 1);
        if (qtx >= tx0 && qtx <= tx1 && qty >= ty0 && qty <= ty1
            && zmb <= wmax_s[q]) {
          unsigned int slot = atomicAdd(&cnt_s[q], 1u);   // LDS atomic, <=256
          idx_s[q][slot] = (unsigned short)t2.z;
        }
      }
    }
    __syncthreads();                       // C: appends visible
    int m = (int)cnt_s[w];
    for (int j = 0; j < m; ++j) {
      int f2 = __builtin_amdgcn_readfirstlane((int)idx_s[w][j]);  // scalar addr
      const float4* fr = (const float4*)(fd + (size_t)f2 * 16);
      float4 A  = fr[0];                   // x0,y0,x1,y1
      float4 Bv = fr[1];                   // x2,y2,rz0,rz1
      float4 Cv = fr[2];                   // rz2,det,c0,c1
      float4 Dv = fr[3];                   // c2,idflag,tilepack,zminbits
      unsigned int zmb = __float_as_uint(Dv.w);
      if (zmb > kz) continue;              // per-lane z-kill (strict)
      float e0 = edgef(A.z, A.w, Bv.x, Bv.y, px, py);
      float e1 = edgef(Bv.x, Bv.y, A.x, A.y, px, py);
      float e2 = edgef(A.x, A.y, A.z, A.w, px, py);
      if (e0 >= 0.f && e1 >= 0.f && e2 >= 0.f) {
        float inva = __fmaf_rn(e0, Cv.z, __fmaf_rn(e1, Cv.w, e2 * Dv.x));
        float zc = __uint_as_float(kz);    // conservative threshold
        unsigned int w13 = __float_as_uint(Dv.y);
        // skip only when inv*zc provably < 1 (err bound ~3e-3 << 5e-3 margin)
        bool pass = (kz >= 0x7F800000u)    // no candidate yet (sentinel bits)
                  | ((w13 >> 24) != 0u) | (inva * zc > 0.995f) | (fabsf(inva) < 1e-4f);
        if (pass) {
          // exact reference chain (bit-identical decision path)
          float rz0 = Bv.z, rz1 = Bv.w, rz2 = Cv.x, det = Cv.y;
          float b0f = __fdiv_rn(e0, det);
          float b1f = __fdiv_rn(e1, det);
          float b2f = __fdiv_rn(e2, det);
          float inv = __fadd_rn(__fadd_rn(__fdiv_rn(b0f, rz0), __fdiv_rn(b1f, rz1)),
                                __fdiv_rn(b2f, rz2));
          if (!(fabsf(inv) > 1e-8f)) inv = 1.0f;
          float zp = __fdiv_rn(1.0f, inv);
          if (zp > 0.1f && zp < 25.0f) {
            unsigned long long key =
                ((unsigned long long)__float_as_uint(zp) << 32)
                | (w13 & 0x00FFFFFFu);
            if (key < best) {
              best = key;
              kz = min(kz, (unsigned int)(best >> 32));
            }
          }
        }
      }
    }
    // eager merge: only if local z can match/beat achieved global z (safe:
    // a strictly-greater z loses regardless of face id)
    if (best != lastw && (unsigned int)(best >> 32) <= gz) {
      atomicMin(&keys[p], best);
      lastw = best;
    }
  }
}

// resolve: one thread per pixel -> images output (exact chain, inline transform)
__global__ __launch_bounds__(256) void resolve_k(const float* __restrict__ cam,
                                                 const float* __restrict__ verts,
                                                 const int* __restrict__ faces,
                                                 const unsigned long long* __restrict__ keys,
                                                 const float* __restrict__ out_tex,
                                                 float* __restrict__ out_img) {
  int p = blockIdx.x * 256 + threadIdx.x;
  if (p >= NPIX) return;
  unsigned long long k = keys[p];
  float c0v = 0.f, c1v = 0.f, c2v = 0.f;
  if (k != SENTINEL) {
    int f = (int)(unsigned int)(k & 0x00FFFFFFULL);
    float bz = __uint_as_float((unsigned int)(k >> 32));
    int xx = p & (SS - 1), yy = p >> 8;
    float px = (float)(2 * xx + 1 - SS) * (1.0f / 256.0f);
    float py = (float)(2 * yy + 1 - SS) * (1.0f / 256.0f);
    float c0 = cam[0], c1 = cam[1], c2 = cam[2];
    int ia = faces[f*3+0], ib = faces[f*3+1], ic = faces[f*3+2];
    float x0 =  __fmul_rn(c0, __fadd_rn(verts[ia*3+0], c1));
    float y0 = -__fmul_rn(c0, __fadd_rn(verts[ia*3+1], c2));
    float z0 =  __fadd_rn(verts[ia*3+2], EYEZ);
    float x1 =  __fmul_rn(c0, __fadd_rn(verts[ib*3+0], c1));
    float y1 = -__fmul_rn(c0, __fadd_rn(verts[ib*3+1], c2));
    float z1 =  __fadd_rn(verts[ib*3+2], EYEZ);
    float x2 =  __fmul_rn(c0, __fadd_rn(verts[ic*3+0], c1));
    float y2 = -__fmul_rn(c0, __fadd_rn(verts[ic*3+1], c2));
    float z2 =  __fadd_rn(verts[ic*3+2], EYEZ);
    float det = edgef(x1, y1, x2, y2, x0, y0);
    float e0 = edgef(x1, y1, x2, y2, px, py);
    float e1 = edgef(x2, y2, x0, y0, px, py);
    float e2 = edgef(x0, y0, x1, y1, px, py);
    float b0 = __fdiv_rn(e0, det);
    float b1 = __fdiv_rn(e1, det);
    float b2 = __fdiv_rn(e2, det);
    float rz0 = (fabsf(z0) > 1e-8f) ? z0 : 1.0f;
    float rz1 = (fabsf(z1) > 1e-8f) ? z1 : 1.0f;
    float rz2 = (fabsf(z2) > 1e-8f) ? z2 : 1.0f;
    float w0 = __fmul_rn(__fdiv_rn(b0, rz0), bz);
    float w1 = __fmul_rn(__fdiv_rn(b1, rz1), bz);
    float w2 = __fmul_rn(__fdiv_rn(b2, rz2), bz);
    float pos0 = fminf(fmaxf(w0, 0.f), 1.f) * 2.f;
    float pos1 = fminf(fmaxf(w1, 0.f), 1.f) * 2.f;
    float pos2 = fminf(fmaxf(w2, 0.f), 1.f) * 2.f;
    float i0f = fminf(fmaxf(floorf(pos0), 0.f), 1.f);
    float i1f = fminf(fmaxf(floorf(pos1), 0.f), 1.f);
    float i2f = fminf(fmaxf(floorf(pos2), 0.f), 1.f);
    float fr0 = fminf(fmaxf(__fsub_rn(pos0, i0f), 0.f), 1.f);
    float fr1 = fminf(fmaxf(__fsub_rn(pos1, i1f), 0.f), 1.f);
    float fr2 = fminf(fmaxf(__fsub_rn(pos2, i2f), 0.f), 1.f);
    int i00 = (int)i0f, i01 = (int)i1f;
    #pragma unroll
    for (int d0 = 0; d0 < 2; ++d0) {
      float wa = d0 ? fr0 : __fsub_rn(1.f, fr0);
      #pragma unroll
      for (int d1 = 0; d1 < 2; ++d1) {
        float wb = d1 ? fr1 : __fsub_rn(1.f, fr1);
        int a = min(i00 + d0, 2);
        int b = min(i01 + d1, 2);
        const float* tp = &out_tex[f * 81 + a * 27 + b * 9];  // k=0 slice
        float wab = __fmul_rn(wa, wb);
        #pragma unroll
        for (int d2 = 0; d2 < 2; ++d2) {
          float wc = d2 ? fr2 : __fsub_rn(1.f, fr2);
          float wgt = __fmul_rn(wab, wc);
          c0v = __fadd_rn(c0v, __fmul_rn(wgt, tp[0]));
          c1v = __fadd_rn(c1v, __fmul_rn(wgt, tp[1]));
          c2v = __fadd_rn(c2v, __fmul_rn(wgt, tp[2]));
        }
      }
    }
  }
  out_img[p]          = c0v;
  out_img[NPIX + p]   = c1v;
  out_img[2*NPIX + p] = c2v;
}

extern "C" void kernel_launch(void* const* d_in, const int* in_sizes, int n_in,
                              void* d_out, int out_size, void* d_ws, size_t ws_size,
                              hipStream_t stream) {
  const float* cam   = (const float*)d_in[0];
  const float* verts = (const float*)d_in[1];
  const float* uv    = (const float*)d_in[2];
  const int*   faces = (const int*)d_in[3];
  float* out_img = (float*)d_out;            // (1,3,256,256)
  float* out_tex = (float*)d_out + 3 * NPIX; // (1,NF,3,3,3,3)

  char* ws = (char*)d_ws;
  unsigned long long* keys = (unsigned long long*)(ws + OFF_KEYS);
  float* fd           = (float*)(ws + OFF_FD);
  unsigned int* phist = (unsigned int*)(ws + OFF_PH);
  uint4* td2          = (uint4*)(ws + OFF_TD2);

  prep_k<<<(NFACE * 9 + 255) / 256, 256, 0, stream>>>(cam, verts, faces, uv,
                                                      fd, phist, keys, out_tex);
  scatter_k<<<1, 1024, 0, stream>>>(fd, phist, td2);
  tile_k<<<NSB * SPLIT, 256, 0, stream>>>(fd, td2, keys);
  resolve_k<<<NPIX / 256, 256, 0, stream>>>(cam, verts, faces, keys, out_tex, out_img);
}